// Round 1
// baseline (990.696 us; speedup 1.0000x reference)
//
#include <hip/hip_runtime.h>
#include <math.h>

#define HW 16384
#define WID 128
#define BB 4
#define CC 21
#define DD 256
#define NA 84      // BB*CC anchors
#define NV 100
#define NN 8400    // NA*NV
#define NPOS 400   // BB*NV same-class columns per row

// ---------------- K1: bilinear 2x upsample + argmax over channels ----------
__global__ void pred_kernel(const float* __restrict__ predict, int* __restrict__ pred) {
  int t = blockIdx.x * blockDim.x + threadIdx.x;   // 0..65535
  int b = t / HW;
  int p = t % HW;
  int y = p / WID, x = p % WID;
  float yin = y * 0.5f - 0.25f;
  float xin = x * 0.5f - 0.25f;
  int y0 = (int)floorf(yin), x0 = (int)floorf(xin);
  float fy = yin - (float)y0, fx = xin - (float)x0;
  int y0c = max(y0, 0), y1c = min(y0 + 1, 63);
  int x0c = max(x0, 0), x1c = min(x0 + 1, 63);
  float w00 = (1.f - fy) * (1.f - fx), w01 = (1.f - fy) * fx;
  float w10 = fy * (1.f - fx),        w11 = fy * fx;
  const float* pb = predict + (size_t)b * CC * 4096;
  float best = -1e30f; int bc = 0;
  for (int c = 0; c < CC; ++c) {
    const float* pc = pb + c * 4096;
    float v = w00 * pc[y0c * 64 + x0c] + w01 * pc[y0c * 64 + x1c]
            + w10 * pc[y1c * 64 + x0c] + w11 * pc[y1c * 64 + x1c];
    if (v > best) { best = v; bc = c; }  // strict > keeps first index (jnp.argmax)
  }
  pred[t] = bc;
}

// ---------------- K2: deterministic hard/easy index selection --------------
// One wave (64 lanes) per (b,c) pair. Ballot-prefix scan over 16384 pixels.
__global__ void select_kernel(const int* __restrict__ pred, const int* __restrict__ labels,
                              int* __restrict__ idx) {
  int pair = blockIdx.x;         // 0..83
  int b = pair / CC, c = pair % CC;
  int lane = threadIdx.x;        // 0..63
  const int* pb = pred + b * HW;
  const int* lb = labels + b * HW;

  // phase 1: counts
  int nh = 0, ne = 0;
  for (int base = 0; base < HW; base += 64) {
    int p = base + lane;
    int pr = pb[p], la = lb[p];
    nh += (pr == c) && (la != c);
    ne += (pr == c) && (la == c);
  }
  for (int o = 32; o; o >>= 1) { nh += __shfl_down(nh, o); ne += __shfl_down(ne, o); }
  nh = __shfl(nh, 0); ne = __shfl(ne, 0);

  const int half = NV / 2;
  int hk;
  if (nh >= half && ne >= half) hk = half;
  else if (nh >= half)          hk = NV - ne;
  else                          hk = nh;
  int ek = NV - hk;
  int total_sel = min(hk, nh) + min(ek, ne);
  int F = NV - total_sel;        // filler count from unselected pixels

  // phase 2: emit (stable order: selected in pixel order, then unselected)
  unsigned long long lt = (lane == 63) ? ~0ull >> 1 : ((1ull << lane) - 1ull);
  lt = (1ull << lane) - 1ull;    // lane<64 so this is fine (lane=63 -> low 63 bits)
  int hbase = 0, ebase = 0, sbase = 0, ubase = 0;
  int* out = idx + pair * NV;
  for (int base = 0; base < HW; base += 64) {
    int p = base + lane;
    int pr = pb[p], la = lb[p];
    bool hard = (pr == c) && (la != c);
    bool easy = (pr == c) && (la == c);
    unsigned long long bh = __ballot(hard), be = __ballot(easy);
    int hr = hbase + __popcll(bh & lt);
    int er = ebase + __popcll(be & lt);
    bool sel = (hard && hr < hk) || (easy && er < ek);
    unsigned long long bs = __ballot(sel);
    int sidx = sbase + __popcll(bs & lt);
    if (sel && sidx < NV) out[sidx] = p;
    bool uns = !sel;
    unsigned long long bu = __ballot(uns);
    int uidx = ubase + __popcll(bu & lt);
    if (uns && uidx < F) out[total_sel + uidx] = p;
    hbase += __popcll(bh); ebase += __popcll(be);
    sbase += __popcll(bs); ubase += __popcll(bu);
  }
}

// ---------------- K3: gather selected pixels + L2 normalize ----------------
// cf[n][d], n = v*84 + a  (matches transpose(1,0,2).reshape)
__global__ void gather_kernel(const float* __restrict__ feats, const int* __restrict__ idx,
                              float* __restrict__ cf) {
  int n = blockIdx.x;            // 0..8399
  int a = n % NA, v = n / NA;
  int b = a / CC;
  int p = idx[a * NV + v];
  int d = threadIdx.x;           // 0..255
  float val = feats[((size_t)(b * DD + d)) * HW + p];
  float ss = val * val;
  for (int o = 32; o; o >>= 1) ss += __shfl_down(ss, o);
  __shared__ float red[4];
  if ((d & 63) == 0) red[d >> 6] = ss;
  __syncthreads();
  float tot = red[0] + red[1] + red[2] + red[3];
  float inv = 1.0f / fmaxf(sqrtf(tot), 1e-12f);
  cf[(size_t)n * DD + d] = val * inv;
}

// ---------------- K4: S = cf@cf^T fused with neg-sum + pos scatter ---------
// 64x64 output tile per block, k tiled by 64. s = dot*10 - 10 (shift m=10
// cancels exactly in the log-prob; self-dot==max==10 for unit vectors).
__global__ __launch_bounds__(256) void gemm_kernel(const float* __restrict__ cf,
                                                   float* __restrict__ neg_sum,
                                                   float* __restrict__ s_pos) {
  __shared__ float sA[64 * 65];
  __shared__ float sB[64 * 65];
  __shared__ float redN[16 * 64];
  int i0 = blockIdx.y * 64;
  int j0 = blockIdx.x * 64;
  int tid = threadIdx.x;
  int tx = tid % 16, ty = tid / 16;
  float acc[4][4] = {};

  for (int k0 = 0; k0 < DD; k0 += 64) {
    int ldty = tid / 16;         // row within 16-row group
    int ldtx = tid % 16;         // float4 column
    for (int l = 0; l < 4; ++l) {
      int rA = min(i0 + l * 16 + ldty, NN - 1);
      int rB = min(j0 + l * 16 + ldty, NN - 1);
      float4 va = *(const float4*)(cf + (size_t)rA * DD + k0 + ldtx * 4);
      float4 vb = *(const float4*)(cf + (size_t)rB * DD + k0 + ldtx * 4);
      int ii = l * 16 + ldty;
      int kk = ldtx * 4;
      sA[(kk + 0) * 65 + ii] = va.x; sA[(kk + 1) * 65 + ii] = va.y;
      sA[(kk + 2) * 65 + ii] = va.z; sA[(kk + 3) * 65 + ii] = va.w;
      sB[(kk + 0) * 65 + ii] = vb.x; sB[(kk + 1) * 65 + ii] = vb.y;
      sB[(kk + 2) * 65 + ii] = vb.z; sB[(kk + 3) * 65 + ii] = vb.w;
    }
    __syncthreads();
    for (int kk = 0; kk < 64; ++kk) {
      float aR[4], bR[4];
      #pragma unroll
      for (int t = 0; t < 4; ++t) aR[t] = sA[kk * 65 + ty * 4 + t];
      #pragma unroll
      for (int t = 0; t < 4; ++t) bR[t] = sB[kk * 65 + tx * 4 + t];
      #pragma unroll
      for (int ti = 0; ti < 4; ++ti)
        #pragma unroll
        for (int tj = 0; tj < 4; ++tj)
          acc[ti][tj] = fmaf(aR[ti], bR[tj], acc[ti][tj]);
    }
    __syncthreads();
  }

  float negpart[4] = {0.f, 0.f, 0.f, 0.f};
  #pragma unroll
  for (int ti = 0; ti < 4; ++ti) {
    int i = i0 + ty * 4 + ti;
    #pragma unroll
    for (int tj = 0; tj < 4; ++tj) {
      int j = j0 + tx * 4 + tj;
      if (i < NN && j < NN) {
        float s = acc[ti][tj] * 10.0f - 10.0f;
        int ci = (i % NA) % CC, cj = (j % NA) % CC;
        if (ci == cj) {
          int pr = (j / NA) * 4 + ((j % NA) / CC);
          s_pos[(size_t)i * NPOS + pr] = s;
        } else {
          negpart[ti] += __expf(s);
        }
      }
    }
  }
  #pragma unroll
  for (int ti = 0; ti < 4; ++ti) redN[tx * 64 + ty * 4 + ti] = negpart[ti];
  __syncthreads();
  if (tid < 64) {
    float s = 0.f;
    #pragma unroll
    for (int t = 0; t < 16; ++t) s += redN[t * 64 + tid];
    int i = i0 + tid;
    if (i < NN) atomicAdd(&neg_sum[i], s);
  }
}

// ---------------- K5: per-row log-prob over the 400 pos columns ------------
__global__ void loss_kernel(const float* __restrict__ s_pos, const float* __restrict__ neg_sum,
                            double* __restrict__ acc) {
  int i = blockIdx.x;            // 0..8399
  int tid = threadIdx.x;         // 0..127
  float ns = neg_sum[i];
  int self = (i / NA) * 4 + ((i % NA) / CC);
  float sum = 0.f;
  for (int k = tid; k < NPOS; k += 128) {
    if (k == self) continue;
    float sp = s_pos[(size_t)i * NPOS + k];
    sum += sp - logf(expf(sp) + ns);
  }
  for (int o = 32; o; o >>= 1) sum += __shfl_down(sum, o);
  __shared__ float r2[2];
  if ((tid & 63) == 0) r2[tid >> 6] = sum;
  __syncthreads();
  if (tid == 0) atomicAdd(acc, (double)((r2[0] + r2[1]) / 399.0));
}

__global__ void final_kernel(const double* __restrict__ acc, float* __restrict__ out) {
  out[0] = (float)(-acc[0] / 8400.0);
}

// ---------------- launch ---------------------------------------------------
extern "C" void kernel_launch(void* const* d_in, const int* in_sizes, int n_in,
                              void* d_out, int out_size, void* d_ws, size_t ws_size,
                              hipStream_t stream) {
  const float* feats   = (const float*)d_in[0];
  const float* predict = (const float*)d_in[1];
  const int*   labels  = (const int*)d_in[2];
  float* out = (float*)d_out;
  char* ws = (char*)d_ws;

  // workspace layout (bytes)
  int*    pred    = (int*)(ws + 0);          //  262144
  int*    idx     = (int*)(ws + 262144);     //   33600
  float*  neg_sum = (float*)(ws + 295936);   //   33600
  double* acc     = (double*)(ws + 329536);  //       8
  float*  cf      = (float*)(ws + 329728);   // 8601600
  float*  s_pos   = (float*)(ws + 8931328);  // 13440000  (end ~22.4 MB)

  hipMemsetAsync(neg_sum, 0, NN * sizeof(float), stream);
  hipMemsetAsync(acc, 0, sizeof(double), stream);

  pred_kernel<<<256, 256, 0, stream>>>(predict, pred);
  select_kernel<<<NA, 64, 0, stream>>>(pred, labels, idx);
  gather_kernel<<<NN, 256, 0, stream>>>(feats, idx, cf);
  gemm_kernel<<<dim3(132, 132), 256, 0, stream>>>(cf, neg_sum, s_pos);
  loss_kernel<<<NN, 128, 0, stream>>>(s_pos, neg_sum, acc);
  final_kernel<<<1, 1, 0, stream>>>(acc, out);
}

// Round 2
// 387.065 us; speedup vs baseline: 2.5595x; 2.5595x over previous
//
#include <hip/hip_runtime.h>
#include <math.h>

#define HW 16384
#define WID 128
#define BB 4
#define CC 21
#define DD 256
#define NA 84      // BB*CC anchors
#define NV 100
#define NN 8400    // NA*NV
#define NPOS 400   // BB*NV same-class columns per row
#define NPAD 8448  // 66 * 128
#define LDK 72     // LDS row stride (bf16) = 64 + 8 pad

typedef __bf16 bf16;
typedef bf16 v8bf __attribute__((ext_vector_type(8)));
typedef float v4f __attribute__((ext_vector_type(4)));

// ---------------- K1: bilinear 2x upsample + argmax over channels ----------
__global__ void pred_kernel(const float* __restrict__ predict, int* __restrict__ pred) {
  int t = blockIdx.x * blockDim.x + threadIdx.x;   // 0..65535
  int b = t / HW;
  int p = t % HW;
  int y = p / WID, x = p % WID;
  float yin = y * 0.5f - 0.25f;
  float xin = x * 0.5f - 0.25f;
  int y0 = (int)floorf(yin), x0 = (int)floorf(xin);
  float fy = yin - (float)y0, fx = xin - (float)x0;
  int y0c = max(y0, 0), y1c = min(y0 + 1, 63);
  int x0c = max(x0, 0), x1c = min(x0 + 1, 63);
  float w00 = (1.f - fy) * (1.f - fx), w01 = (1.f - fy) * fx;
  float w10 = fy * (1.f - fx),        w11 = fy * fx;
  const float* pb = predict + (size_t)b * CC * 4096;
  float best = -1e30f; int bc = 0;
  for (int c = 0; c < CC; ++c) {
    const float* pc = pb + c * 4096;
    float v = w00 * pc[y0c * 64 + x0c] + w01 * pc[y0c * 64 + x1c]
            + w10 * pc[y1c * 64 + x0c] + w11 * pc[y1c * 64 + x1c];
    if (v > best) { best = v; bc = c; }  // strict > keeps first index (jnp.argmax)
  }
  pred[t] = bc;
}

// ---------------- K2: deterministic hard/easy index selection --------------
__global__ void select_kernel(const int* __restrict__ pred, const int* __restrict__ labels,
                              int* __restrict__ idx) {
  int pair = blockIdx.x;         // 0..83
  int b = pair / CC, c = pair % CC;
  int lane = threadIdx.x;        // 0..63
  const int* pb = pred + b * HW;
  const int* lb = labels + b * HW;

  int nh = 0, ne = 0;
  for (int base = 0; base < HW; base += 64) {
    int p = base + lane;
    int pr = pb[p], la = lb[p];
    nh += (pr == c) && (la != c);
    ne += (pr == c) && (la == c);
  }
  for (int o = 32; o; o >>= 1) { nh += __shfl_down(nh, o); ne += __shfl_down(ne, o); }
  nh = __shfl(nh, 0); ne = __shfl(ne, 0);

  const int half = NV / 2;
  int hk;
  if (nh >= half && ne >= half) hk = half;
  else if (nh >= half)          hk = NV - ne;
  else                          hk = nh;
  int ek = NV - hk;
  int total_sel = min(hk, nh) + min(ek, ne);
  int F = NV - total_sel;

  unsigned long long lt = (1ull << lane) - 1ull;
  int hbase = 0, ebase = 0, sbase = 0, ubase = 0;
  int* out = idx + pair * NV;
  for (int base = 0; base < HW; base += 64) {
    int p = base + lane;
    int pr = pb[p], la = lb[p];
    bool hard = (pr == c) && (la != c);
    bool easy = (pr == c) && (la == c);
    unsigned long long bh = __ballot(hard), be = __ballot(easy);
    int hr = hbase + __popcll(bh & lt);
    int er = ebase + __popcll(be & lt);
    bool sel = (hard && hr < hk) || (easy && er < ek);
    unsigned long long bs = __ballot(sel);
    int sidx = sbase + __popcll(bs & lt);
    if (sel && sidx < NV) out[sidx] = p;
    bool uns = !sel;
    unsigned long long bu = __ballot(uns);
    int uidx = ubase + __popcll(bu & lt);
    if (uns && uidx < F) out[total_sel + uidx] = p;
    hbase += __popcll(bh); ebase += __popcll(be);
    sbase += __popcll(bs); ubase += __popcll(bu);
  }
}

// ---------------- K3: gather selected pixels + L2 normalize -> bf16 --------
__global__ void gather_kernel(const float* __restrict__ feats, const int* __restrict__ idx,
                              bf16* __restrict__ cf) {
  int n = blockIdx.x;            // 0..8399
  int a = n % NA, v = n / NA;
  int b = a / CC;
  int p = idx[a * NV + v];
  int d = threadIdx.x;           // 0..255
  float val = feats[((size_t)(b * DD + d)) * HW + p];
  float ss = val * val;
  for (int o = 32; o; o >>= 1) ss += __shfl_down(ss, o);
  __shared__ float red[4];
  if ((d & 63) == 0) red[d >> 6] = ss;
  __syncthreads();
  float tot = red[0] + red[1] + red[2] + red[3];
  float inv = 1.0f / fmaxf(sqrtf(tot), 1e-12f);
  cf[(size_t)n * DD + d] = (bf16)(val * inv);
}

// ---------------- K4: MFMA bf16 GEMM S=cf@cf^T + neg-sum + pos scatter -----
// 128x128 tile / block, 4 waves (2x2), each wave 4x4 frags of 16x16x32.
// s = dot*10 - 10 (fixed shift m=10 cancels in log-prob; self-dot ~= 1).
__global__ __launch_bounds__(256) void gemm_kernel(const bf16* __restrict__ cf,
                                                   float* __restrict__ neg_sum,
                                                   float* __restrict__ s_pos) {
  __shared__ __align__(16) bf16 sA[128 * LDK];
  __shared__ __align__(16) bf16 sB[128 * LDK];
  int i0 = blockIdx.y * 128;
  int j0 = blockIdx.x * 128;
  int tid = threadIdx.x;
  int wave = tid >> 6, lane = tid & 63;
  int wi = wave >> 1, wj = wave & 1;
  int m = lane & 15, q = lane >> 4;

  v4f acc[4][4] = {};

  int srow = tid >> 3;           // 0..31
  int scol = (tid & 7) * 8;      // bf16 col offset, 16B chunks

  for (int k0 = 0; k0 < DD; k0 += 64) {
    #pragma unroll
    for (int rd = 0; rd < 4; ++rd) {
      int r = rd * 32 + srow;
      uint4 va = *(const uint4*)(cf + (size_t)(i0 + r) * DD + k0 + scol);
      uint4 vb = *(const uint4*)(cf + (size_t)(j0 + r) * DD + k0 + scol);
      *(uint4*)(sA + r * LDK + scol) = va;
      *(uint4*)(sB + r * LDK + scol) = vb;
    }
    __syncthreads();
    #pragma unroll
    for (int kk = 0; kk < 2; ++kk) {
      v8bf af[4], bfr[4];
      #pragma unroll
      for (int t = 0; t < 4; ++t)
        af[t] = *(const v8bf*)(sA + (wi * 64 + t * 16 + m) * LDK + kk * 32 + q * 8);
      #pragma unroll
      for (int t = 0; t < 4; ++t)
        bfr[t] = *(const v8bf*)(sB + (wj * 64 + t * 16 + m) * LDK + kk * 32 + q * 8);
      #pragma unroll
      for (int ti = 0; ti < 4; ++ti)
        #pragma unroll
        for (int tj = 0; tj < 4; ++tj)
          acc[ti][tj] = __builtin_amdgcn_mfma_f32_16x16x32_bf16(af[ti], bfr[tj], acc[ti][tj], 0, 0, 0);
    }
    __syncthreads();
  }

  // ---- epilogue: C/D layout col=lane&15, row=q*4+reg ----
  int iw0 = i0 + wi * 64;
  int jw0 = j0 + wj * 64;

  int ci_arr[16];
  #pragma unroll
  for (int ti = 0; ti < 4; ++ti)
    #pragma unroll
    for (int r = 0; r < 4; ++r)
      ci_arr[ti * 4 + r] = ((iw0 + ti * 16 + q * 4 + r) % NA) % CC;
  int cj_arr[4], pr_arr[4];
  #pragma unroll
  for (int tj = 0; tj < 4; ++tj) {
    int j = jw0 + tj * 16 + m;
    cj_arr[tj] = (j % NA) % CC;
    pr_arr[tj] = (j / NA) * 4 + (j % NA) / CC;
  }

  float negp[16];
  #pragma unroll
  for (int t = 0; t < 16; ++t) negp[t] = 0.f;

  #pragma unroll
  for (int ti = 0; ti < 4; ++ti) {
    #pragma unroll
    for (int r = 0; r < 4; ++r) {
      int i = iw0 + ti * 16 + q * 4 + r;
      if (i >= NN) continue;
      int ci = ci_arr[ti * 4 + r];
      #pragma unroll
      for (int tj = 0; tj < 4; ++tj) {
        int j = jw0 + tj * 16 + m;
        if (j >= NN) continue;
        float s = acc[ti][tj][r] * 10.0f - 10.0f;
        if (ci == cj_arr[tj]) {
          s_pos[(size_t)i * NPOS + pr_arr[tj]] = s;
        } else {
          negp[ti * 4 + r] += __expf(s);
        }
      }
    }
  }

  // ---- per-row cross-lane reduction of neg partials via LDS ----
  float* red = (float*)sA + wave * (64 * 17);
  #pragma unroll
  for (int ti = 0; ti < 4; ++ti)
    #pragma unroll
    for (int r = 0; r < 4; ++r)
      red[(ti * 16 + q * 4 + r) * 17 + m] = negp[ti * 4 + r];
  __syncthreads();
  {
    float s = 0.f;
    #pragma unroll
    for (int t = 0; t < 16; ++t) s += red[lane * 17 + t];
    int i = iw0 + lane;
    if (i < NN) atomicAdd(&neg_sum[i], s);
  }
}

// ---------------- K5: per-row log-prob over the 400 pos columns ------------
__global__ void loss_kernel(const float* __restrict__ s_pos, const float* __restrict__ neg_sum,
                            double* __restrict__ acc) {
  int i = blockIdx.x;            // 0..8399
  int tid = threadIdx.x;         // 0..127
  float ns = neg_sum[i];
  int self = (i / NA) * 4 + ((i % NA) / CC);
  float sum = 0.f;
  for (int k = tid; k < NPOS; k += 128) {
    if (k == self) continue;
    float sp = s_pos[(size_t)i * NPOS + k];
    sum += sp - logf(expf(sp) + ns);
  }
  for (int o = 32; o; o >>= 1) sum += __shfl_down(sum, o);
  __shared__ float r2[2];
  if ((tid & 63) == 0) r2[tid >> 6] = sum;
  __syncthreads();
  if (tid == 0) atomicAdd(acc, (double)((r2[0] + r2[1]) / 399.0));
}

__global__ void final_kernel(const double* __restrict__ acc, float* __restrict__ out) {
  out[0] = (float)(-acc[0] / 8400.0);
}

// ---------------- launch ---------------------------------------------------
extern "C" void kernel_launch(void* const* d_in, const int* in_sizes, int n_in,
                              void* d_out, int out_size, void* d_ws, size_t ws_size,
                              hipStream_t stream) {
  const float* feats   = (const float*)d_in[0];
  const float* predict = (const float*)d_in[1];
  const int*   labels  = (const int*)d_in[2];
  float* out = (float*)d_out;
  char* ws = (char*)d_ws;

  // workspace layout (bytes)
  int*    pred    = (int*)(ws + 0);          //   262144
  int*    idx     = (int*)(ws + 262144);     //    33600
  float*  neg_sum = (float*)(ws + 295936);   //    33600
  double* acc     = (double*)(ws + 329536);  //        8
  bf16*   cf      = (bf16*)(ws + 329728);    //  4325376 (NPAD*256*2)
  float*  s_pos   = (float*)(ws + 4655104);  // 13440000 (end ~18.1 MB)

  hipMemsetAsync(neg_sum, 0, NN * sizeof(float), stream);
  hipMemsetAsync(acc, 0, sizeof(double), stream);
  // zero bf16 padding rows 8400..8447 (0x0000 == bf16 zero)
  hipMemsetAsync((char*)(cf + (size_t)NN * DD), 0, (size_t)(NPAD - NN) * DD * 2, stream);

  pred_kernel<<<256, 256, 0, stream>>>(predict, pred);
  select_kernel<<<NA, 64, 0, stream>>>(pred, labels, idx);
  gather_kernel<<<NN, 256, 0, stream>>>(feats, idx, cf);
  gemm_kernel<<<dim3(NPAD / 128, NPAD / 128), 256, 0, stream>>>(cf, neg_sum, s_pos);
  loss_kernel<<<NN, 128, 0, stream>>>(s_pos, neg_sum, acc);
  final_kernel<<<1, 1, 0, stream>>>(acc, out);
}

// Round 3
// 300.728 us; speedup vs baseline: 3.2943x; 1.2871x over previous
//
#include <hip/hip_runtime.h>
#include <math.h>

#define HW 16384
#define WID 128
#define BB 4
#define CC 21
#define DD 256
#define NA 84      // BB*CC anchors
#define NV 100
#define NN 8400    // NA*NV
#define NPOS 400   // BB*NV same-class columns per row
#define NPAD 8448  // 66 * 128
#define LDK 72     // LDS row stride (bf16) = 64 + 8 pad
#define LBLK 336   // loss blocks; each covers 25 rows
#define LROWS 25

typedef __bf16 bf16;
typedef bf16 v8bf __attribute__((ext_vector_type(8)));
typedef float v4f __attribute__((ext_vector_type(4)));

// ---------------- K1: bilinear 2x upsample + argmax over channels ----------
__global__ void pred_kernel(const float* __restrict__ predict, int* __restrict__ pred) {
  int t = blockIdx.x * blockDim.x + threadIdx.x;   // 0..65535
  int b = t / HW;
  int p = t % HW;
  int y = p / WID, x = p % WID;
  float yin = y * 0.5f - 0.25f;
  float xin = x * 0.5f - 0.25f;
  int y0 = (int)floorf(yin), x0 = (int)floorf(xin);
  float fy = yin - (float)y0, fx = xin - (float)x0;
  int y0c = max(y0, 0), y1c = min(y0 + 1, 63);
  int x0c = max(x0, 0), x1c = min(x0 + 1, 63);
  float w00 = (1.f - fy) * (1.f - fx), w01 = (1.f - fy) * fx;
  float w10 = fy * (1.f - fx),        w11 = fy * fx;
  const float* pb = predict + (size_t)b * CC * 4096;
  float best = -1e30f; int bc = 0;
  for (int c = 0; c < CC; ++c) {
    const float* pc = pb + c * 4096;
    float v = w00 * pc[y0c * 64 + x0c] + w01 * pc[y0c * 64 + x1c]
            + w10 * pc[y1c * 64 + x0c] + w11 * pc[y1c * 64 + x1c];
    if (v > best) { best = v; bc = c; }  // strict > keeps first index (jnp.argmax)
  }
  pred[t] = bc;
}

// ---------------- K2: deterministic hard/easy index selection --------------
__global__ void select_kernel(const int* __restrict__ pred, const int* __restrict__ labels,
                              int* __restrict__ idx) {
  int pair = blockIdx.x;         // 0..83
  int b = pair / CC, c = pair % CC;
  int lane = threadIdx.x;        // 0..63
  const int* pb = pred + b * HW;
  const int* lb = labels + b * HW;

  int nh = 0, ne = 0;
  for (int base = 0; base < HW; base += 64) {
    int p = base + lane;
    int pr = pb[p], la = lb[p];
    nh += (pr == c) && (la != c);
    ne += (pr == c) && (la == c);
  }
  for (int o = 32; o; o >>= 1) { nh += __shfl_down(nh, o); ne += __shfl_down(ne, o); }
  nh = __shfl(nh, 0); ne = __shfl(ne, 0);

  const int half = NV / 2;
  int hk;
  if (nh >= half && ne >= half) hk = half;
  else if (nh >= half)          hk = NV - ne;
  else                          hk = nh;
  int ek = NV - hk;
  int total_sel = min(hk, nh) + min(ek, ne);
  int F = NV - total_sel;

  unsigned long long lt = (1ull << lane) - 1ull;
  int hbase = 0, ebase = 0, sbase = 0, ubase = 0;
  int* out = idx + pair * NV;
  for (int base = 0; base < HW; base += 64) {
    int p = base + lane;
    int pr = pb[p], la = lb[p];
    bool hard = (pr == c) && (la != c);
    bool easy = (pr == c) && (la == c);
    unsigned long long bh = __ballot(hard), be = __ballot(easy);
    int hr = hbase + __popcll(bh & lt);
    int er = ebase + __popcll(be & lt);
    bool sel = (hard && hr < hk) || (easy && er < ek);
    unsigned long long bs = __ballot(sel);
    int sidx = sbase + __popcll(bs & lt);
    if (sel && sidx < NV) out[sidx] = p;
    bool uns = !sel;
    unsigned long long bu = __ballot(uns);
    int uidx = ubase + __popcll(bu & lt);
    if (uns && uidx < F) out[total_sel + uidx] = p;
    hbase += __popcll(bh); ebase += __popcll(be);
    sbase += __popcll(bs); ubase += __popcll(bu);
  }
}

// ---------------- K3: gather selected pixels + L2 normalize -> bf16 --------
__global__ void gather_kernel(const float* __restrict__ feats, const int* __restrict__ idx,
                              bf16* __restrict__ cf) {
  int n = blockIdx.x;            // 0..8399
  int a = n % NA, v = n / NA;
  int b = a / CC;
  int p = idx[a * NV + v];
  int d = threadIdx.x;           // 0..255
  float val = feats[((size_t)(b * DD + d)) * HW + p];
  float ss = val * val;
  for (int o = 32; o; o >>= 1) ss += __shfl_down(ss, o);
  __shared__ float red[4];
  if ((d & 63) == 0) red[d >> 6] = ss;
  __syncthreads();
  float tot = red[0] + red[1] + red[2] + red[3];
  float inv = 1.0f / fmaxf(sqrtf(tot), 1e-12f);
  cf[(size_t)n * DD + d] = (bf16)(val * inv);
}

// ---------------- K4: MFMA bf16 GEMM S=cf@cf^T + neg-sum + pos scatter -----
__global__ __launch_bounds__(256) void gemm_kernel(const bf16* __restrict__ cf,
                                                   float* __restrict__ neg_sum,
                                                   float* __restrict__ s_pos) {
  __shared__ __align__(16) bf16 sA[128 * LDK];
  __shared__ __align__(16) bf16 sB[128 * LDK];
  int i0 = blockIdx.y * 128;
  int j0 = blockIdx.x * 128;
  int tid = threadIdx.x;
  int wave = tid >> 6, lane = tid & 63;
  int wi = wave >> 1, wj = wave & 1;
  int m = lane & 15, q = lane >> 4;

  v4f acc[4][4] = {};

  int srow = tid >> 3;           // 0..31
  int scol = (tid & 7) * 8;      // bf16 col offset, 16B chunks

  for (int k0 = 0; k0 < DD; k0 += 64) {
    #pragma unroll
    for (int rd = 0; rd < 4; ++rd) {
      int r = rd * 32 + srow;
      uint4 va = *(const uint4*)(cf + (size_t)(i0 + r) * DD + k0 + scol);
      uint4 vb = *(const uint4*)(cf + (size_t)(j0 + r) * DD + k0 + scol);
      *(uint4*)(sA + r * LDK + scol) = va;
      *(uint4*)(sB + r * LDK + scol) = vb;
    }
    __syncthreads();
    #pragma unroll
    for (int kk = 0; kk < 2; ++kk) {
      v8bf af[4], bfr[4];
      #pragma unroll
      for (int t = 0; t < 4; ++t)
        af[t] = *(const v8bf*)(sA + (wi * 64 + t * 16 + m) * LDK + kk * 32 + q * 8);
      #pragma unroll
      for (int t = 0; t < 4; ++t)
        bfr[t] = *(const v8bf*)(sB + (wj * 64 + t * 16 + m) * LDK + kk * 32 + q * 8);
      #pragma unroll
      for (int ti = 0; ti < 4; ++ti)
        #pragma unroll
        for (int tj = 0; tj < 4; ++tj)
          acc[ti][tj] = __builtin_amdgcn_mfma_f32_16x16x32_bf16(af[ti], bfr[tj], acc[ti][tj], 0, 0, 0);
    }
    __syncthreads();
  }

  // ---- epilogue: C/D layout col=lane&15, row=q*4+reg ----
  int iw0 = i0 + wi * 64;
  int jw0 = j0 + wj * 64;

  int ci_arr[16];
  #pragma unroll
  for (int ti = 0; ti < 4; ++ti)
    #pragma unroll
    for (int r = 0; r < 4; ++r)
      ci_arr[ti * 4 + r] = ((iw0 + ti * 16 + q * 4 + r) % NA) % CC;
  int cj_arr[4], pr_arr[4];
  #pragma unroll
  for (int tj = 0; tj < 4; ++tj) {
    int j = jw0 + tj * 16 + m;
    cj_arr[tj] = (j % NA) % CC;
    pr_arr[tj] = (j / NA) * 4 + (j % NA) / CC;
  }

  float negp[16];
  #pragma unroll
  for (int t = 0; t < 16; ++t) negp[t] = 0.f;

  #pragma unroll
  for (int ti = 0; ti < 4; ++ti) {
    #pragma unroll
    for (int r = 0; r < 4; ++r) {
      int i = iw0 + ti * 16 + q * 4 + r;
      if (i >= NN) continue;
      int ci = ci_arr[ti * 4 + r];
      #pragma unroll
      for (int tj = 0; tj < 4; ++tj) {
        int j = jw0 + tj * 16 + m;
        if (j >= NN) continue;
        float s = acc[ti][tj][r] * 10.0f - 10.0f;
        if (ci == cj_arr[tj]) {
          s_pos[(size_t)i * NPOS + pr_arr[tj]] = s;
        } else {
          negp[ti * 4 + r] += __expf(s);
        }
      }
    }
  }

  // ---- per-row cross-lane reduction of neg partials via LDS ----
  float* red = (float*)sA + wave * (64 * 17);
  #pragma unroll
  for (int ti = 0; ti < 4; ++ti)
    #pragma unroll
    for (int r = 0; r < 4; ++r)
      red[(ti * 16 + q * 4 + r) * 17 + m] = negp[ti * 4 + r];
  __syncthreads();
  {
    float s = 0.f;
    #pragma unroll
    for (int t = 0; t < 16; ++t) s += red[lane * 17 + t];
    int i = iw0 + lane;
    if (i < NN) atomicAdd(&neg_sum[i], s);
  }
}

// ---------------- K5: per-row log-prob over the 400 pos columns ------------
// 336 blocks x 256 threads, 25 rows/block, NO global atomics: one double
// partial per block, summed by final_kernel. (R2: 8400 same-address double
// atomics serialized at ~12ns = the whole 105us.)
__global__ __launch_bounds__(256) void loss_kernel(const float* __restrict__ s_pos,
                                                   const float* __restrict__ neg_sum,
                                                   double* __restrict__ partials) {
  int blk = blockIdx.x;
  int tid = threadIdx.x;
  int r0 = blk * LROWS;
  float sum = 0.f;
  for (int e = tid; e < LROWS * NPOS; e += 256) {
    int i = r0 + e / NPOS;
    int k = e % NPOS;
    int self = (i / NA) * 4 + ((i % NA) / CC);
    if (k == self) continue;
    float ns = neg_sum[i];
    float sp = s_pos[(size_t)i * NPOS + k];
    sum += sp - logf(expf(sp) + ns);
  }
  for (int o = 32; o; o >>= 1) sum += __shfl_down(sum, o);
  __shared__ float r2[4];
  if ((tid & 63) == 0) r2[tid >> 6] = sum;
  __syncthreads();
  if (tid == 0) partials[blk] = (double)(r2[0] + r2[1] + r2[2] + r2[3]);
}

__global__ void final_kernel(const double* __restrict__ partials, float* __restrict__ out) {
  int lane = threadIdx.x;        // 64
  double s = 0.0;
  for (int t = lane; t < LBLK; t += 64) s += partials[t];
  for (int o = 32; o; o >>= 1) s += __shfl_down(s, o);
  if (lane == 0) out[0] = (float)(-s / 399.0 / 8400.0);
}

// ---------------- launch ---------------------------------------------------
extern "C" void kernel_launch(void* const* d_in, const int* in_sizes, int n_in,
                              void* d_out, int out_size, void* d_ws, size_t ws_size,
                              hipStream_t stream) {
  const float* feats   = (const float*)d_in[0];
  const float* predict = (const float*)d_in[1];
  const int*   labels  = (const int*)d_in[2];
  float* out = (float*)d_out;
  char* ws = (char*)d_ws;

  // workspace layout (bytes)
  int*    pred     = (int*)(ws + 0);          //   262144
  int*    idx      = (int*)(ws + 262144);     //    33600
  float*  neg_sum  = (float*)(ws + 295936);   //    33600
  double* partials = (double*)(ws + 329536);  //     2688
  bf16*   cf       = (bf16*)(ws + 332288);    //  4325376 (NPAD*256*2)
  float*  s_pos    = (float*)(ws + 4657664);  // 13440000 (end ~18.1 MB)

  hipMemsetAsync(neg_sum, 0, NN * sizeof(float), stream);
  // zero bf16 padding rows 8400..8447 (0x0000 == bf16 zero)
  hipMemsetAsync((char*)(cf + (size_t)NN * DD), 0, (size_t)(NPAD - NN) * DD * 2, stream);

  pred_kernel<<<256, 256, 0, stream>>>(predict, pred);
  select_kernel<<<NA, 64, 0, stream>>>(pred, labels, idx);
  gather_kernel<<<NN, 256, 0, stream>>>(feats, idx, cf);
  gemm_kernel<<<dim3(NPAD / 128, NPAD / 128), 256, 0, stream>>>(cf, neg_sum, s_pos);
  loss_kernel<<<LBLK, 256, 0, stream>>>(s_pos, neg_sum, partials);
  final_kernel<<<1, 64, 0, stream>>>(partials, out);
}

// Round 4
// 271.192 us; speedup vs baseline: 3.6531x; 1.1089x over previous
//
#include <hip/hip_runtime.h>
#include <math.h>

#define HW 16384
#define WID 128
#define BB 4
#define CC 21
#define DD 256
#define NA 84      // BB*CC anchors
#define NV 100
#define NN 8400    // NA*NV
#define NPOS 400   // BB*NV same-class columns per row
#define NPAD 8448  // 66 * 128
#define LDK 72     // LDS row stride (bf16) = 64 + 8 pad
#define LBLK 336   // loss blocks; each covers 25 rows
#define LROWS 25
#define NTILE 66   // NPAD/128
#define NTRI 2211  // NTILE*(NTILE+1)/2

typedef __bf16 bf16;
typedef bf16 v8bf __attribute__((ext_vector_type(8)));
typedef float v4f __attribute__((ext_vector_type(4)));

// ---------------- K1: bilinear 2x upsample + argmax over channels ----------
__global__ void pred_kernel(const float* __restrict__ predict, int* __restrict__ pred) {
  int t = blockIdx.x * blockDim.x + threadIdx.x;   // 0..65535
  int b = t / HW;
  int p = t % HW;
  int y = p / WID, x = p % WID;
  float yin = y * 0.5f - 0.25f;
  float xin = x * 0.5f - 0.25f;
  int y0 = (int)floorf(yin), x0 = (int)floorf(xin);
  float fy = yin - (float)y0, fx = xin - (float)x0;
  int y0c = max(y0, 0), y1c = min(y0 + 1, 63);
  int x0c = max(x0, 0), x1c = min(x0 + 1, 63);
  float w00 = (1.f - fy) * (1.f - fx), w01 = (1.f - fy) * fx;
  float w10 = fy * (1.f - fx),        w11 = fy * fx;
  const float* pb = predict + (size_t)b * CC * 4096;
  float best = -1e30f; int bc = 0;
  for (int c = 0; c < CC; ++c) {
    const float* pc = pb + c * 4096;
    float v = w00 * pc[y0c * 64 + x0c] + w01 * pc[y0c * 64 + x1c]
            + w10 * pc[y1c * 64 + x0c] + w11 * pc[y1c * 64 + x1c];
    if (v > best) { best = v; bc = c; }  // strict > keeps first index (jnp.argmax)
  }
  pred[t] = bc;
}

// ---------------- K2: parallel hard/easy index selection -------------------
// One 256-thread block per (b,c). Each thread owns 64 contiguous pixels as
// hard/easy bitmasks (single memory pass); two block scans give global
// prefix ranks; in-register emit. (R3: the 84-wave serial ballot scan was
// latency-bound.)
__global__ __launch_bounds__(256) void select_kernel(const int* __restrict__ pred,
                                                     const int* __restrict__ labels,
                                                     int* __restrict__ idx) {
  int pair = blockIdx.x;         // 0..83
  int b = pair / CC, c = pair % CC;
  int tid = threadIdx.x;         // 0..255
  const int4* pb = (const int4*)(pred + b * HW) + tid * 16;
  const int4* lb = (const int4*)(labels + b * HW) + tid * 16;

  unsigned long long hm = 0ull, em = 0ull;
  #pragma unroll
  for (int g = 0; g < 16; ++g) {
    int4 p4 = pb[g];
    int4 l4 = lb[g];
    unsigned long long h =
        ((unsigned long long)((p4.x == c) & (l4.x != c)))      |
        ((unsigned long long)((p4.y == c) & (l4.y != c)) << 1) |
        ((unsigned long long)((p4.z == c) & (l4.z != c)) << 2) |
        ((unsigned long long)((p4.w == c) & (l4.w != c)) << 3);
    unsigned long long e =
        ((unsigned long long)((p4.x == c) & (l4.x == c)))      |
        ((unsigned long long)((p4.y == c) & (l4.y == c)) << 1) |
        ((unsigned long long)((p4.z == c) & (l4.z == c)) << 2) |
        ((unsigned long long)((p4.w == c) & (l4.w == c)) << 3);
    hm |= h << (g * 4);
    em |= e << (g * 4);
  }
  int nh_t = __popcll(hm), ne_t = __popcll(em);

  __shared__ int sh[256], se[256], ss[256];
  sh[tid] = nh_t; se[tid] = ne_t;
  __syncthreads();
  for (int off = 1; off < 256; off <<= 1) {
    int vh = (tid >= off) ? sh[tid - off] : 0;
    int ve = (tid >= off) ? se[tid - off] : 0;
    __syncthreads();
    sh[tid] += vh; se[tid] += ve;
    __syncthreads();
  }
  int h_excl = sh[tid] - nh_t, e_excl = se[tid] - ne_t;
  int nh = sh[255], ne = se[255];

  const int half = NV / 2;
  int hk;
  if (nh >= half && ne >= half) hk = half;
  else if (nh >= half)          hk = NV - ne;
  else                          hk = nh;
  int ek = NV - hk;

  int takeh = min(max(hk - h_excl, 0), nh_t);
  int takee = min(max(ek - e_excl, 0), ne_t);
  int sel_t = takeh + takee;
  ss[tid] = sel_t;
  __syncthreads();
  for (int off = 1; off < 256; off <<= 1) {
    int vs = (tid >= off) ? ss[tid - off] : 0;
    __syncthreads();
    ss[tid] += vs;
    __syncthreads();
  }
  int s_excl = ss[tid] - sel_t;
  int total_sel = ss[255];
  int F = NV - total_sel;
  int u_excl = tid * 64 - s_excl;

  int* out = idx + pair * NV;
  int sc = 0, uc = 0, hc = 0, ec = 0;
  for (int l = 0; l < 64; ++l) {
    int p = tid * 64 + l;
    int hard = (int)((hm >> l) & 1ull);
    int easy = (int)((em >> l) & 1ull);
    bool sel = (hard && hc < takeh) || (easy && ec < takee);
    hc += hard; ec += easy;
    if (sel) {
      if (s_excl + sc < NV) out[s_excl + sc] = p;
      sc++;
    } else {
      if (u_excl + uc < F) out[total_sel + u_excl + uc] = p;
      uc++;
    }
  }
}

// ---------------- K3: gather selected pixels + L2 normalize -> bf16 --------
__global__ void gather_kernel(const float* __restrict__ feats, const int* __restrict__ idx,
                              bf16* __restrict__ cf) {
  int n = blockIdx.x;            // 0..8399
  int a = n % NA, v = n / NA;
  int b = a / CC;
  int p = idx[a * NV + v];
  int d = threadIdx.x;           // 0..255
  float val = feats[((size_t)(b * DD + d)) * HW + p];
  float ss = val * val;
  for (int o = 32; o; o >>= 1) ss += __shfl_down(ss, o);
  __shared__ float red[4];
  if ((d & 63) == 0) red[d >> 6] = ss;
  __syncthreads();
  float tot = red[0] + red[1] + red[2] + red[3];
  float inv = 1.0f / fmaxf(sqrtf(tot), 1e-12f);
  cf[(size_t)n * DD + d] = (bf16)(val * inv);
}

// ---------------- K4: symmetric MFMA bf16 GEMM (lower triangle only) -------
// S = cf@cf^T is exactly symmetric (identical MFMA K-chains). 2211 tile
// blocks; off-diagonal blocks emit both (i,j) and (j,i): pos scatter both
// ways, exp(s) into row AND column partials. Row reduce shfl_xor(1,2,4,8)
// over m-lanes; col reduce shfl_xor(16,32) over q-lanes.
__global__ __launch_bounds__(256) void gemm_kernel(const bf16* __restrict__ cf,
                                                   float* __restrict__ neg_sum,
                                                   float* __restrict__ s_pos) {
  __shared__ __align__(16) bf16 sA[128 * LDK];
  __shared__ __align__(16) bf16 sB[128 * LDK];
  int t = blockIdx.x;            // 0..NTRI-1
  int I = (int)((sqrtf(8.0f * t + 1.0f) - 1.0f) * 0.5f);
  while ((I + 1) * (I + 2) / 2 <= t) ++I;
  while (I * (I + 1) / 2 > t) --I;
  int J = t - I * (I + 1) / 2;   // J <= I
  int i0 = I * 128;
  int j0 = J * 128;
  bool diag = (I == J);

  int tid = threadIdx.x;
  int wave = tid >> 6, lane = tid & 63;
  int wi = wave >> 1, wj = wave & 1;
  int m = lane & 15, q = lane >> 4;

  v4f acc[4][4] = {};

  int srow = tid >> 3;           // 0..31
  int scol = (tid & 7) * 8;      // bf16 col offset, 16B chunks

  for (int k0 = 0; k0 < DD; k0 += 64) {
    #pragma unroll
    for (int rd = 0; rd < 4; ++rd) {
      int r = rd * 32 + srow;
      uint4 va = *(const uint4*)(cf + (size_t)(i0 + r) * DD + k0 + scol);
      uint4 vb = *(const uint4*)(cf + (size_t)(j0 + r) * DD + k0 + scol);
      *(uint4*)(sA + r * LDK + scol) = va;
      *(uint4*)(sB + r * LDK + scol) = vb;
    }
    __syncthreads();
    #pragma unroll
    for (int kk = 0; kk < 2; ++kk) {
      v8bf af[4], bfr[4];
      #pragma unroll
      for (int tt = 0; tt < 4; ++tt)
        af[tt] = *(const v8bf*)(sA + (wi * 64 + tt * 16 + m) * LDK + kk * 32 + q * 8);
      #pragma unroll
      for (int tt = 0; tt < 4; ++tt)
        bfr[tt] = *(const v8bf*)(sB + (wj * 64 + tt * 16 + m) * LDK + kk * 32 + q * 8);
      #pragma unroll
      for (int ti = 0; ti < 4; ++ti)
        #pragma unroll
        for (int tj = 0; tj < 4; ++tj)
          acc[ti][tj] = __builtin_amdgcn_mfma_f32_16x16x32_bf16(af[ti], bfr[tj], acc[ti][tj], 0, 0, 0);
    }
    __syncthreads();
  }

  // ---- epilogue: C/D layout col=lane&15, row=q*4+reg ----
  int iw0 = i0 + wi * 64;
  int jw0 = j0 + wj * 64;

  int ci_arr[16], pri_arr[16];
  #pragma unroll
  for (int ti = 0; ti < 4; ++ti)
    #pragma unroll
    for (int r = 0; r < 4; ++r) {
      int i = iw0 + ti * 16 + q * 4 + r;
      ci_arr[ti * 4 + r] = (i % NA) % CC;
      pri_arr[ti * 4 + r] = (i / NA) * 4 + (i % NA) / CC;
    }
  int cj_arr[4], prj_arr[4];
  #pragma unroll
  for (int tj = 0; tj < 4; ++tj) {
    int j = jw0 + tj * 16 + m;
    cj_arr[tj] = (j % NA) % CC;
    prj_arr[tj] = (j / NA) * 4 + (j % NA) / CC;
  }

  float rowp[16];
  float colp[4] = {0.f, 0.f, 0.f, 0.f};
  #pragma unroll
  for (int tt = 0; tt < 16; ++tt) rowp[tt] = 0.f;

  #pragma unroll
  for (int ti = 0; ti < 4; ++ti) {
    #pragma unroll
    for (int r = 0; r < 4; ++r) {
      int i = iw0 + ti * 16 + q * 4 + r;
      if (i >= NN) continue;
      int ci = ci_arr[ti * 4 + r];
      #pragma unroll
      for (int tj = 0; tj < 4; ++tj) {
        int j = jw0 + tj * 16 + m;
        if (j >= NN) continue;
        float s = acc[ti][tj][r] * 10.0f - 10.0f;
        if (ci == cj_arr[tj]) {
          s_pos[(size_t)i * NPOS + prj_arr[tj]] = s;
          if (!diag) s_pos[(size_t)j * NPOS + pri_arr[ti * 4 + r]] = s;
        } else {
          float e = __expf(s);
          rowp[ti * 4 + r] += e;
          if (!diag) colp[tj] += e;
        }
      }
    }
  }

  // ---- row reduction across the 16 m-lanes ----
  #pragma unroll
  for (int tt = 0; tt < 16; ++tt) {
    float v = rowp[tt];
    v += __shfl_xor(v, 1); v += __shfl_xor(v, 2);
    v += __shfl_xor(v, 4); v += __shfl_xor(v, 8);
    rowp[tt] = v;
  }
  if (m == 0) {
    #pragma unroll
    for (int ti = 0; ti < 4; ++ti)
      #pragma unroll
      for (int r = 0; r < 4; ++r) {
        int i = iw0 + ti * 16 + q * 4 + r;
        if (i < NN) atomicAdd(&neg_sum[i], rowp[ti * 4 + r]);
      }
  }
  // ---- column reduction across the 4 q-lanes (off-diagonal only) ----
  if (!diag) {
    #pragma unroll
    for (int tj = 0; tj < 4; ++tj) {
      float v = colp[tj];
      v += __shfl_xor(v, 16); v += __shfl_xor(v, 32);
      colp[tj] = v;
    }
    if (q == 0) {
      #pragma unroll
      for (int tj = 0; tj < 4; ++tj) {
        int j = jw0 + tj * 16 + m;
        if (j < NN) atomicAdd(&neg_sum[j], colp[tj]);
      }
    }
  }
}

// ---------------- K5: per-row log-prob over the 400 pos columns ------------
__global__ __launch_bounds__(256) void loss_kernel(const float* __restrict__ s_pos,
                                                   const float* __restrict__ neg_sum,
                                                   double* __restrict__ partials) {
  int blk = blockIdx.x;
  int tid = threadIdx.x;
  int r0 = blk * LROWS;
  float sum = 0.f;
  for (int e = tid; e < LROWS * NPOS; e += 256) {
    int i = r0 + e / NPOS;
    int k = e % NPOS;
    int self = (i / NA) * 4 + ((i % NA) / CC);
    if (k == self) continue;
    float ns = neg_sum[i];
    float sp = s_pos[(size_t)i * NPOS + k];
    sum += sp - logf(expf(sp) + ns);
  }
  for (int o = 32; o; o >>= 1) sum += __shfl_down(sum, o);
  __shared__ float r2[4];
  if ((tid & 63) == 0) r2[tid >> 6] = sum;
  __syncthreads();
  if (tid == 0) partials[blk] = (double)(r2[0] + r2[1] + r2[2] + r2[3]);
}

__global__ void final_kernel(const double* __restrict__ partials, float* __restrict__ out) {
  int lane = threadIdx.x;        // 64
  double s = 0.0;
  for (int t = lane; t < LBLK; t += 64) s += partials[t];
  for (int o = 32; o; o >>= 1) s += __shfl_down(s, o);
  if (lane == 0) out[0] = (float)(-s / 399.0 / 8400.0);
}

// ---------------- launch ---------------------------------------------------
extern "C" void kernel_launch(void* const* d_in, const int* in_sizes, int n_in,
                              void* d_out, int out_size, void* d_ws, size_t ws_size,
                              hipStream_t stream) {
  const float* feats   = (const float*)d_in[0];
  const float* predict = (const float*)d_in[1];
  const int*   labels  = (const int*)d_in[2];
  float* out = (float*)d_out;
  char* ws = (char*)d_ws;

  // workspace layout (bytes)
  int*    pred     = (int*)(ws + 0);          //   262144
  int*    idx      = (int*)(ws + 262144);     //    33600
  float*  neg_sum  = (float*)(ws + 295936);   //    33600
  double* partials = (double*)(ws + 329536);  //     2688
  bf16*   cf       = (bf16*)(ws + 332288);    //  4325376 (NPAD*256*2)
  float*  s_pos    = (float*)(ws + 4657664);  // 13440000 (end ~18.1 MB)

  hipMemsetAsync(neg_sum, 0, NN * sizeof(float), stream);
  // zero bf16 padding rows 8400..8447 (0x0000 == bf16 zero)
  hipMemsetAsync((char*)(cf + (size_t)NN * DD), 0, (size_t)(NPAD - NN) * DD * 2, stream);

  pred_kernel<<<256, 256, 0, stream>>>(predict, pred);
  select_kernel<<<NA, 256, 0, stream>>>(pred, labels, idx);
  gather_kernel<<<NN, 256, 0, stream>>>(feats, idx, cf);
  gemm_kernel<<<NTRI, 256, 0, stream>>>(cf, neg_sum, s_pos);
  loss_kernel<<<LBLK, 256, 0, stream>>>(s_pos, neg_sum, partials);
  final_kernel<<<1, 64, 0, stream>>>(partials, out);
}